// Round 3
// baseline (748.402 us; speedup 1.0000x reference)
//
#include <hip/hip_runtime.h>

#define N_DIM 12288
#define D_DIM 16
#define TILE  256

typedef float f4 __attribute__((ext_vector_type(4)));
typedef float f2 __attribute__((ext_vector_type(2)));

// out[0] = 0 (d_out is poisoned 0xAA before every timed call)
__global__ void zero_kernel(float* __restrict__ out) {
    out[0] = 0.0f;
}

// lmbd1 * (sum|U1| + sum|U2|)
__global__ void l1_kernel(const float* __restrict__ U1,
                          const float* __restrict__ U2,
                          const float* __restrict__ lmbd,
                          float* __restrict__ out) {
    const int M = N_DIM * D_DIM;
    int idx = blockIdx.x * blockDim.x + threadIdx.x;
    int stride = gridDim.x * blockDim.x;
    float s = 0.0f;
    for (int i = idx; i < M; i += stride)
        s += fabsf(U1[i]) + fabsf(U2[i]);
    #pragma unroll
    for (int off = 32; off; off >>= 1)
        s += __shfl_down(s, off, 64);
    __shared__ float ws[4];
    int lane = threadIdx.x & 63;
    int wave = threadIdx.x >> 6;
    if (lane == 0) ws[wave] = s;
    __syncthreads();
    if (threadIdx.x == 0)
        atomicAdd(out, lmbd[0] * (ws[0] + ws[1] + ws[2] + ws[3]));
}

// sum_ij A_ij * (-log_sigmoid(<U1_i, U2_j>)).
// Block: 256x256 tile of A. Thread: owns 4 columns (U2 rows) in registers
// as packed f2 pairs -> v_pk_fma_f32 halves dot-product issue count.
// 4-row software pipeline: 4 nontemporal A loads in flight per wave.
// U1 row loads are wave-uniform (readfirstlane) -> scalar s_load path.
// Scores >= 0 (U1,U2 in [0,1)) so -logsig(x) = ln2*log2(1+exp2(-x*log2e)).
__global__ __launch_bounds__(256, 4)
void loss_kernel(const float* __restrict__ A,
                 const float* __restrict__ U1,
                 const float* __restrict__ U2,
                 float* __restrict__ out) {
    const int t    = threadIdx.x;
    const int lane = t & 63;
    const int wave = t >> 6;
    const int r0   = blockIdx.y * TILE;
    const int c0   = blockIdx.x * TILE;
    const int cl   = lane * 4;          // thread's first local column

    // U2 fragment: 4 columns x 16 k in 64 VGPRs, packed as column-pairs so
    // the k-loop runs on v_pk_fma_f32. Wave reads contiguous 16 KB: coalesced.
    f2 u2p01[D_DIM], u2p23[D_DIM];
    {
        const f4* p0 = (const f4*)(U2 + (size_t)(c0 + cl + 0) * D_DIM);
        const f4* p1 = (const f4*)(U2 + (size_t)(c0 + cl + 1) * D_DIM);
        const f4* p2 = (const f4*)(U2 + (size_t)(c0 + cl + 2) * D_DIM);
        const f4* p3 = (const f4*)(U2 + (size_t)(c0 + cl + 3) * D_DIM);
        #pragma unroll
        for (int q = 0; q < 4; ++q) {
            f4 a = p0[q], b = p1[q], c = p2[q], d = p3[q];
            #pragma unroll
            for (int e = 0; e < 4; ++e) {
                u2p01[q * 4 + e] = (f2){a[e], b[e]};
                u2p23[q * 4 + e] = (f2){c[e], d[e]};
            }
        }
    }

    // Wave-uniform U1 row pointer -> scalar (SMEM) loads.
    const int urow0 = __builtin_amdgcn_readfirstlane(r0 + wave * 64);
    const float* __restrict__ up = U1 + (size_t)urow0 * D_DIM;
    const float* __restrict__ ap = A  + (size_t)urow0 * N_DIM + (size_t)(c0 + cl);

    f2 acc01 = {0.f, 0.f};   // accumulates A * log2(1 + exp2(-s*log2e))
    f2 acc23 = {0.f, 0.f};

    const float L2E = 1.4426950408889634f;

    for (int rb = 0; rb < 16; ++rb) {
        // 4 A-row loads in flight (4 KB/wave) before any compute consumes them.
        f4 av[4];
        av[0] = __builtin_nontemporal_load((const f4*)(ap));
        av[1] = __builtin_nontemporal_load((const f4*)(ap + (size_t)N_DIM));
        av[2] = __builtin_nontemporal_load((const f4*)(ap + 2 * (size_t)N_DIM));
        av[3] = __builtin_nontemporal_load((const f4*)(ap + 3 * (size_t)N_DIM));

        #pragma unroll
        for (int r = 0; r < 4; ++r) {
            const float* u = up + r * D_DIM;     // uniform -> s_load
            f2 sd01 = {0.f, 0.f}, sd23 = {0.f, 0.f};
            #pragma unroll
            for (int k = 0; k < D_DIM; ++k) {
                float u1k = u[k];
                f2 uu = {u1k, u1k};
                sd01 = __builtin_elementwise_fma(uu, u2p01[k], sd01);  // v_pk_fma_f32
                sd23 = __builtin_elementwise_fma(uu, u2p23[k], sd23);
            }
            f2 x01 = sd01 * (f2){-L2E, -L2E};    // v_pk_mul_f32
            f2 x23 = sd23 * (f2){-L2E, -L2E};
            float e0 = __builtin_amdgcn_exp2f(x01.x);
            float e1 = __builtin_amdgcn_exp2f(x01.y);
            float e2 = __builtin_amdgcn_exp2f(x23.x);
            float e3 = __builtin_amdgcn_exp2f(x23.y);
            f2 o01 = (f2){e0, e1} + (f2){1.f, 1.f};   // v_pk_add_f32
            f2 o23 = (f2){e2, e3} + (f2){1.f, 1.f};
            f2 l01 = {__builtin_amdgcn_logf(o01.x), __builtin_amdgcn_logf(o01.y)};
            f2 l23 = {__builtin_amdgcn_logf(o23.x), __builtin_amdgcn_logf(o23.y)};
            acc01 = __builtin_elementwise_fma((f2){av[r].x, av[r].y}, l01, acc01);
            acc23 = __builtin_elementwise_fma((f2){av[r].z, av[r].w}, l23, acc23);
        }
        ap += 4 * (size_t)N_DIM;
        up += 4 * D_DIM;
    }

    float part = (acc01.x + acc01.y + acc23.x + acc23.y) * 0.69314718055994531f;

    // wave reduce -> block reduce -> one atomic per block
    #pragma unroll
    for (int off = 32; off; off >>= 1)
        part += __shfl_down(part, off, 64);
    __shared__ float wsum[4];
    if (lane == 0) wsum[wave] = part;
    __syncthreads();
    if (t == 0)
        atomicAdd(out, wsum[0] + wsum[1] + wsum[2] + wsum[3]);
}

extern "C" void kernel_launch(void* const* d_in, const int* in_sizes, int n_in,
                              void* d_out, int out_size, void* d_ws, size_t ws_size,
                              hipStream_t stream) {
    const float* A    = (const float*)d_in[0];
    const float* U1   = (const float*)d_in[1];
    const float* U2   = (const float*)d_in[2];
    const float* lmbd = (const float*)d_in[3];
    float* out = (float*)d_out;

    zero_kernel<<<1, 64, 0, stream>>>(out);
    l1_kernel<<<256, 256, 0, stream>>>(U1, U2, lmbd, out);

    dim3 grid(N_DIM / TILE, N_DIM / TILE);   // 48 x 48 tiles
    loss_kernel<<<grid, 256, 0, stream>>>(A, U1, U2, out);
}